// Round 8
// baseline (86.340 us; speedup 1.0000x reference)
//
#include <hip/hip_runtime.h>
#include <math.h>

#define D_DIM 256
#define TILE  128
#define BKE   128           // fp8 k-elements per K-step (128 B per LDS row)
#define LDS_BYTES (TILE * BKE)          // 16 KB per tile buffer
#define LDS_ALLOC (LDS_BYTES + 7168)    // pad -> ~48 KB/block total -> 3 blocks/CU

typedef __attribute__((ext_vector_type(4))) int   i32x4;
typedef __attribute__((ext_vector_type(8))) int   i32x8;
typedef __attribute__((ext_vector_type(4))) float f32x4;

#define AS_GLOBAL(p) ((const __attribute__((address_space(1))) void*)(p))
#define AS_LDS(p)    ((__attribute__((address_space(3))) void*)(p))

// ---------------------------------------------------------------------------
// f32 -> OCP e4m3fn (RNE). Inputs are unit-row elements, |x| <= 1.
// Linear (subnormal + first normal octaves) region a < 2^-5: code = rne(a*512).
// Normal region: rebias bit-trick with RNE at bit 20. (validated r5, absmax 0)
__device__ __forceinline__ unsigned int f2e4m3(float f) {
    unsigned int u = __float_as_uint(f);
    unsigned int s = (u >> 24) & 0x80u;
    float a = fabsf(f);
    unsigned int code;
    if (a < 0.03125f) {
        code = __float2uint_rn(a * 512.0f);        // 0..16, exact linear region
    } else {
        unsigned int x = u & 0x7fffffffu;
        unsigned int r = x - (120u << 23);         // rebias: exp-7 -> e4m3 exp
        r += 0x7ffffu + ((r >> 20) & 1u);          // RNE at bit 20
        code = r >> 20;
        if (code > 0x7eu) code = 0x7eu;            // paranoia saturate
    }
    return code | s;
}

__device__ __forceinline__ unsigned int pack_e4m3_4(float4 v) {
    return f2e4m3(v.x) | (f2e4m3(v.y) << 8) | (f2e4m3(v.z) << 16) | (f2e4m3(v.w) << 24);
}

// ---------------------------------------------------------------------------
// Kernel A: per-wave row normalize (validated r2-r5). Block=256 (4 waves),
// wave w -> row i = blockIdx.x*4+w. float4 loads, shuffle reductions.
// Writes fp8 Xq=[a_n;b_n], f32 SQ, unique-slot align partial.
__global__ __launch_bounds__(256) void normalize_kernel(
        const float* __restrict__ A, const float* __restrict__ Bm,
        unsigned int* __restrict__ Xq, float* __restrict__ SQ,
        float* __restrict__ partials, int B_rows) {
    __shared__ float red[4];
    int lane = threadIdx.x & 63;
    int w    = threadIdx.x >> 6;
    int i    = blockIdx.x * 4 + w;

    const float4* A4 = (const float4*)(A + (size_t)i * D_DIM);
    const float4* B4 = (const float4*)(Bm + (size_t)i * D_DIM);
    float4 av = A4[lane];
    float4 bv = B4[lane];

    float sa = av.x*av.x + av.y*av.y + av.z*av.z + av.w*av.w;
    float sb = bv.x*bv.x + bv.y*bv.y + bv.z*bv.z + bv.w*bv.w;
    #pragma unroll
    for (int off = 32; off > 0; off >>= 1) {
        sa += __shfl_xor(sa, off, 64);
        sb += __shfl_xor(sb, off, 64);
    }
    float dena = fmaxf(sqrtf(sa), 1e-12f);
    float denb = fmaxf(sqrtf(sb), 1e-12f);
    float ia = 1.0f / dena, ib = 1.0f / denb;

    float4 an = {av.x*ia, av.y*ia, av.z*ia, av.w*ia};
    float4 bn = {bv.x*ib, bv.y*ib, bv.z*ib, bv.w*ib};

    Xq[(size_t)i * 64 + lane]            = pack_e4m3_4(an);
    Xq[(size_t)(B_rows + i) * 64 + lane] = pack_e4m3_4(bn);

    float dx = an.x-bn.x, dy = an.y-bn.y, dz = an.z-bn.z, dw = an.w-bn.w;
    float sd = dx*dx + dy*dy + dz*dz + dw*dw;
    #pragma unroll
    for (int off = 32; off > 0; off >>= 1) sd += __shfl_down(sd, off, 64);

    if (lane == 0) {
        SQ[i]          = sa * ia * ia;
        SQ[B_rows + i] = sb * ib * ib;
        red[w] = sd;
    }
    __syncthreads();
    if (threadIdx.x == 0)
        partials[blockIdx.x] = red[0]+red[1]+red[2]+red[3];
}

// ---------------------------------------------------------------------------
// Kernel B: uniformity via MX-fp8 MFMA Gram (validated r5). r6 change:
// accumulators SEEDED with -(sq_i+sq_j)/2 so acc_final = dot-(si+sj)/2 =
// -d2/2 and the epilogue is just sum of exp2(C*acc) — no clamp (off-diag
// d2 >= ~1 always; diagonal deviation contributes ~2e-8 to the loss),
// no LDS reads in the epilogue, no per-element adds.
__device__ __forceinline__ i32x4 lds_read16(const unsigned char* base, int r, int g) {
    int off = r * BKE + ((g ^ (r & 7)) << 4);
    return *reinterpret_cast<const i32x4*>(base + off);
}

__global__ __launch_bounds__(256, 3) void uniform_mfma_kernel(
        const unsigned char* __restrict__ Xq, const float* __restrict__ SQ,
        float* __restrict__ partials, int n_panels) {
    __shared__ __align__(16) unsigned char As[LDS_ALLOC];  // 16 KB used + pad
    __shared__ __align__(16) unsigned char Bs[LDS_ALLOC];
    __shared__ float sqa[TILE], sqb[TILE], red[4];

    int t    = threadIdx.x;
    int lane = t & 63;
    int w    = t >> 6;       // 0..3
    int wr   = w >> 1;       // A half: rows wr*64
    int wc   = w & 1;        // B half: rows wc*64

    // closed-form triangle decode (validated r5)
    int bid = blockIdx.x;
    float nn = 2.0f * n_panels + 1.0f;
    int g = (int)((nn - sqrtf(nn * nn - 8.0f * (float)bid)) * 0.5f);
    #define TRI_START(i) (((i) * (2 * n_panels - (i) + 1)) >> 1)
    if (TRI_START(g + 1) <= bid) ++g;
    else if (TRI_START(g) > bid) --g;
    int ib = g;
    int jb = ib + (bid - TRI_START(ib));
    #undef TRI_START

    int rowA0 = ib * TILE, rowB0 = jb * TILE;
    if (t < TILE) sqa[t]        = SQ[rowA0 + t];
    else          sqb[t - TILE] = SQ[rowB0 + t - TILE];
    __syncthreads();   // sqa/sqb visible for seeding

    // Seed acc[m][n][reg] = -(sq_i + sq_j)/2 per the 16x16 C layout
    // (col = lane&15, row = (lane>>4)*4 + reg — validated r4/r5).
    int col = lane & 15;
    int rhi = (lane >> 4) * 4;
    f32x4 acc[4][4];
    #pragma unroll
    for (int m = 0; m < 4; ++m)
        #pragma unroll
        for (int n = 0; n < 4; ++n)
            #pragma unroll
            for (int reg = 0; reg < 4; ++reg) {
                int il = wr * 64 + m * 16 + rhi + reg;
                int jl = wc * 64 + n * 16 + col;
                acc[m][n][reg] = -0.5f * (sqa[il] + sqb[jl]);
            }

    for (int k0 = 0; k0 < D_DIM; k0 += BKE) {
        __syncthreads();   // prev-iter LDS reads done
        // STAGE (validated r5): wave w stages rows [w*32, w*32+32) of both
        // tiles; linear LDS dest (global_load_lds 16B), inverse-swizzled src.
        #pragma unroll
        for (int it = 0; it < 4; ++it) {
            int row = w * 32 + it * 8 + (lane >> 3);
            int gsw = ((lane & 7) ^ (row & 7)) << 4;   // source byte offset
            const unsigned char* sA = Xq + (size_t)(rowA0 + row) * D_DIM + k0 + gsw;
            const unsigned char* sB = Xq + (size_t)(rowB0 + row) * D_DIM + k0 + gsw;
            unsigned char* dA = As + (w * 32 + it * 8) * BKE;
            unsigned char* dB = Bs + (w * 32 + it * 8) * BKE;
            __builtin_amdgcn_global_load_lds(AS_GLOBAL(sA), AS_LDS(dA), 16, 0, 0);
            __builtin_amdgcn_global_load_lds(AS_GLOBAL(sB), AS_LDS(dB), 16, 0, 0);
        }
        __syncthreads();   // staged data visible (compiler drains vmcnt)

        // COMPUTE (validated r5): lane k-chunk (lane>>4)*32 -> granules 2q,2q+1
        int q  = lane >> 4;
        int g0 = q << 1;
        i32x8 a[4], b[4];
        #pragma unroll
        for (int m = 0; m < 4; ++m) {
            int r = wr * 64 + m * 16 + (lane & 15);
            i32x4 lo = lds_read16(As, r, g0);
            i32x4 hi = lds_read16(As, r, g0 + 1);
            a[m] = (i32x8){lo.x, lo.y, lo.z, lo.w, hi.x, hi.y, hi.z, hi.w};
        }
        #pragma unroll
        for (int n = 0; n < 4; ++n) {
            int r = wc * 64 + n * 16 + (lane & 15);
            i32x4 lo = lds_read16(Bs, r, g0);
            i32x4 hi = lds_read16(Bs, r, g0 + 1);
            b[n] = (i32x8){lo.x, lo.y, lo.z, lo.w, hi.x, hi.y, hi.z, hi.w};
        }
        #pragma unroll
        for (int m = 0; m < 4; ++m)
            #pragma unroll
            for (int n = 0; n < 4; ++n)
                acc[m][n] = __builtin_amdgcn_mfma_scale_f32_16x16x128_f8f6f4(
                    a[m], b[n], acc[m][n],
                    0, 0,                       // cbsz/blgp: A,B fmt = fp8
                    0, 0x7f7f7f7f,              // opsel_a, scale_a (E8M0 1.0)
                    0, 0x7f7f7f7f);             // opsel_b, scale_b
    }

    // Epilogue: acc = dot - (sq_i+sq_j)/2 = -d2/2; e = exp(-2*d2) =
    // exp2(C*acc), C = 4*log2(e). exp2f lowers to a single v_exp_f32.
    // 3 ops/element, 4 partial sums for ILP.
    const float C = 5.770780163f;
    float s0 = 0.0f, s1 = 0.0f, s2 = 0.0f, s3 = 0.0f;
    #pragma unroll
    for (int m = 0; m < 4; ++m)
        #pragma unroll
        for (int n = 0; n < 4; ++n) {
            s0 += exp2f(C * acc[m][n][0]);
            s1 += exp2f(C * acc[m][n][1]);
            s2 += exp2f(C * acc[m][n][2]);
            s3 += exp2f(C * acc[m][n][3]);
        }
    float s = (s0 + s1) + (s2 + s3);
    if (ib != jb) s *= 2.0f;

    #pragma unroll
    for (int off = 32; off > 0; off >>= 1) s += __shfl_down(s, off, 64);
    if (lane == 0) red[w] = s;
    __syncthreads();
    if (t == 0)
        partials[1024 + blockIdx.x] = red[0]+red[1]+red[2]+red[3];  // unique slot
}

// ---------------------------------------------------------------------------
// Finalize: sum 1024 align partials + n_blocks uniform partials, one block.
__global__ __launch_bounds__(256) void finalize_kernel(
        const float* __restrict__ partials, float* __restrict__ out,
        int B_rows, int n_blocks) {
    __shared__ float reda[4], redu[4];
    int t = threadIdx.x;
    float al = 0.0f, un = 0.0f;
    for (int i = t; i < 1024; i += 256)      al += partials[i];
    for (int i = t; i < n_blocks; i += 256)  un += partials[1024 + i];
    #pragma unroll
    for (int off = 32; off > 0; off >>= 1) {
        al += __shfl_down(al, off, 64);
        un += __shfl_down(un, off, 64);
    }
    if ((t & 63) == 0) { reda[t >> 6] = al; redu[t >> 6] = un; }
    __syncthreads();
    if (t == 0) {
        float sal = reda[0]+reda[1]+reda[2]+reda[3];
        float sun = redu[0]+redu[1]+redu[2]+redu[3];
        float n = (float)(2 * B_rows);
        out[0] = sal / (float)B_rows + (sun - n) / (n * (n - 1.0f));
    }
}

// ---------------------------------------------------------------------------
extern "C" void kernel_launch(void* const* d_in, const int* in_sizes, int n_in,
                              void* d_out, int out_size, void* d_ws, size_t ws_size,
                              hipStream_t stream) {
    const float* A  = (const float*)d_in[0];
    const float* Bm = (const float*)d_in[1];
    float* out = (float*)d_out;

    int B_rows = in_sizes[0] / D_DIM;   // 4096
    int n_tot  = 2 * B_rows;            // 8192

    // ws layout: Xq (fp8 n*256 = 2 MB) | SQ (f32 n) | partials (f32 1024+2080)
    unsigned char* Xq = (unsigned char*)d_ws;
    float* SQ       = (float*)(Xq + (size_t)n_tot * D_DIM);
    float* partials = SQ + n_tot;

    normalize_kernel<<<B_rows / 4, 256, 0, stream>>>(A, Bm, (unsigned int*)Xq,
                                                     SQ, partials, B_rows);

    int n_panels = n_tot / TILE;                    // 64
    int n_blocks = n_panels * (n_panels + 1) / 2;   // 2080
    uniform_mfma_kernel<<<n_blocks, 256, 0, stream>>>(Xq, SQ, partials, n_panels);

    finalize_kernel<<<1, 256, 0, stream>>>(partials, out, B_rows, n_blocks);
}